// Round 12
// baseline (254.614 us; speedup 1.0000x reference)
//
#include <hip/hip_runtime.h>
#include <hip/hip_fp16.h>
#include <stdint.h>

// ---------------------------------------------------------------------------
// ClusterPolicyNetwork. R18: R17 + per-wave ks STAGGER in score_kernel.
// R17 (4 waves/SIMD) was null #7: occupancy falsified as bottleneck. Counters
// close at: MFMA-busy == dense floor (29us), LDS 49%, VALU 29%, no pipe
// saturated. Remaining theory: CONVOY QUEUEING — 16 waves/CU run identical
// code, resync on shared stalls, and burst 64 ds_read_b128 into the LDS
// queue each ks (+~400cy effective latency). Fix: wave wv sweeps
// ks=(kk+2*wv)&15 so concurrent waves read different ks-slices (uniform LDS
// arrivals). FP-sum reorder only — inside tolerance. Single change vs R17.
// Launches: proj_fused -> attn_one -> score_kernel (3).
// d_out: matching[1M]|coord[32]|attn_w[1M]
// ---------------------------------------------------------------------------

typedef __attribute__((ext_vector_type(4))) float floatx4;
typedef __attribute__((ext_vector_type(16))) float floatx16;
typedef __attribute__((ext_vector_type(8))) _Float16 half8;

// workspace offsets (bytes)
#define OFF_QKV  0x000000u    // 1024*384*4
#define OFF_Q16  0x180000u    // 1024*128*2
#define OFF_K16  0x1C0000u    // 1024*128*2
#define OFF_V16  0x200000u    // 128*1024*2 (V^T, d-major)
#define OFF_T1H  0x280000u    // 1024*256*2 (f16, includes +b1)
#define OFF_N1F  0x300000u    // 1024*256*2 (f16, MFMA B-fragment layout)
#define OFF_W2F  0x380000u    // 65536 (f16 MFMA frags, 32x32 layout)
#define OFF_GS   0x398000u    // 128*4

__device__ __forceinline__ unsigned pkadd(unsigned a, unsigned b) {
    unsigned r; asm("v_pk_add_f16 %0, %1, %2" : "=v"(r) : "v"(a), "v"(b)); return r;
}
__device__ __forceinline__ unsigned pkmax(unsigned a, unsigned b) {
    unsigned r; asm("v_pk_max_f16 %0, %1, %2" : "=v"(r) : "v"(a), "v"(b)); return r;
}
__device__ __forceinline__ unsigned pk2h(float a, float b) {
    return (unsigned)__half_as_ushort(__float2half(a)) |
           ((unsigned)__half_as_ushort(__float2half(b)) << 16);
}
__device__ __forceinline__ float h2f(unsigned short u) {
    return __half2float(__ushort_as_half(u));
}
__device__ __forceinline__ unsigned short f2h(float v) {
    return __half_as_ushort(__float2half(v));
}
// P-LDS swizzled byte offset: row-major [64 rows][2048 B], XOR bank swizzle
__device__ __forceinline__ int plds(int row, int kb) {
    return row * 2048 + (((kb & ~15) ^ ((row & 7) << 4))) + (kb & 15);
}

// ---------------------------------------------------------------------------
// fp32 GEMM tile body: C = scale*(A @ B^T) [+ bias], 64x64 tile, 256 thr.
// SIDE: also emit f16 side-copies (q16/k16 row-major, v16t d-major).
// ---------------------------------------------------------------------------
template<bool BIAS, bool F16OUT, bool SIDE>
__device__ __forceinline__ void gemm_dev(
    const float* __restrict__ A, int lda,
    const float* __restrict__ B, int ldb,
    const float* __restrict__ bias,
    void* __restrict__ Cv, int ldc, int K, float scale,
    int m0, int n0, float (*As)[64], float (*Bs)[64],
    unsigned short* __restrict__ q16o,
    unsigned short* __restrict__ k16o,
    unsigned short* __restrict__ v16o)
{
    const int tid = threadIdx.x;
    const int tx = tid & 15, ty = tid >> 4;
    const int lr = tid >> 2;
    const int lk = (tid & 3) * 4;
    float c[4][4] = {};

    for (int k0 = 0; k0 < K; k0 += 16) {
        float4 a  = *(const float4*)&A[(long)(m0 + lr) * lda + k0 + lk];
        float4 bb = *(const float4*)&B[(long)(n0 + lr) * ldb + k0 + lk];
        __syncthreads();
        As[lk + 0][lr] = a.x;  As[lk + 1][lr] = a.y;  As[lk + 2][lr] = a.z;  As[lk + 3][lr] = a.w;
        Bs[lk + 0][lr] = bb.x; Bs[lk + 1][lr] = bb.y; Bs[lk + 2][lr] = bb.z; Bs[lk + 3][lr] = bb.w;
        __syncthreads();
#pragma unroll
        for (int k = 0; k < 16; k++) {
            float4 av = *(const float4*)&As[k][ty * 4];
            float4 bv = *(const float4*)&Bs[k][tx * 4];
            c[0][0] += av.x * bv.x; c[0][1] += av.x * bv.y; c[0][2] += av.x * bv.z; c[0][3] += av.x * bv.w;
            c[1][0] += av.y * bv.x; c[1][1] += av.y * bv.y; c[1][2] += av.y * bv.z; c[1][3] += av.y * bv.w;
            c[2][0] += av.z * bv.x; c[2][1] += av.z * bv.y; c[2][2] += av.z * bv.z; c[2][3] += av.z * bv.w;
            c[3][0] += av.w * bv.x; c[3][1] += av.w * bv.y; c[3][2] += av.w * bv.z; c[3][3] += av.w * bv.w;
        }
    }

    float bsv[4] = {0.f, 0.f, 0.f, 0.f};
    if (BIAS) {
        float4 t = *(const float4*)&bias[n0 + tx * 4];
        bsv[0] = t.x; bsv[1] = t.y; bsv[2] = t.z; bsv[3] = t.w;
    }
    const int gcol = n0 + tx * 4;
#pragma unroll
    for (int i = 0; i < 4; i++) {
        float v0 = c[i][0] * scale + bsv[0];
        float v1 = c[i][1] * scale + bsv[1];
        float v2 = c[i][2] * scale + bsv[2];
        float v3 = c[i][3] * scale + bsv[3];
        long m = m0 + ty * 4 + i;
        if (F16OUT) {
            unsigned short* Cp = (unsigned short*)Cv;
            ushort4 o;
            o.x = f2h(v0); o.y = f2h(v1); o.z = f2h(v2); o.w = f2h(v3);
            *(ushort4*)&Cp[m * ldc + n0 + tx * 4] = o;
        } else {
            float* Cp = (float*)Cv;
            *(float4*)&Cp[m * ldc + n0 + tx * 4] = make_float4(v0, v1, v2, v3);
        }
        if (SIDE) {
            ushort4 o;
            o.x = f2h(v0); o.y = f2h(v1); o.z = f2h(v2); o.w = f2h(v3);
            if (gcol < 128) {
                *(ushort4*)&q16o[m * 128 + gcol] = o;
            } else if (gcol < 256) {
                *(ushort4*)&k16o[m * 128 + (gcol - 128)] = o;
            } else {
                v16o[(size_t)(gcol - 256 + 0) * 1024 + m] = o.x;
                v16o[(size_t)(gcol - 256 + 1) * 1024 + m] = o.y;
                v16o[(size_t)(gcol - 256 + 2) * 1024 + m] = o.z;
                v16o[(size_t)(gcol - 256 + 3) * 1024 + m] = o.w;
            }
        }
    }
}

// ---------------------------------------------------------------------------
// Launch 1: qkv gemm (96, +f16 sides) + t1h gemm (64) + w2prep (16) + gs zero
// w2prep emits the 32x32x16 A-fragment layout (R14-verified):
//   frag id f = ks*4 + ot;  w2f[(f*64+lane)*8+j] =
//   f16(W2[ot*32 + (lane&31)][ks*16 + (lane>>5)*8 + j])
// ---------------------------------------------------------------------------
__launch_bounds__(256)
__global__ void proj_fused(const float* __restrict__ node, const float* __restrict__ ipw,
                           const float* __restrict__ ipb,
                           const float* __restrict__ task, const float* __restrict__ W1,
                           const float* __restrict__ b1, const float* __restrict__ W2,
                           float* __restrict__ qkv, unsigned short* __restrict__ t1h,
                           unsigned short* __restrict__ w2f, float* __restrict__ gs,
                           unsigned short* __restrict__ q16,
                           unsigned short* __restrict__ k16,
                           unsigned short* __restrict__ v16t)
{
    __shared__ float As[16][64], Bs[16][64];
    const int bid = blockIdx.x;
    if (bid < 96) {
        gemm_dev<true, false, true>(node, 128, ipw, 128, ipb, qkv, 384, 128, 1.0f,
                                    (bid & 15) * 64, (bid >> 4) * 64, As, Bs,
                                    q16, k16, v16t);
    } else if (bid < 160) {
        const int b = bid - 96;
        gemm_dev<true, true, false>(task, 128, W1, 256, b1, t1h, 256, 128, 1.0f,
                                    (b & 15) * 64, (b >> 4) * 64, As, Bs,
                                    nullptr, nullptr, nullptr);
    } else if (bid < 176) {
        const int gtid = (bid - 160) * 256 + threadIdx.x;  // 0..4095
        const int lane = gtid & 63, frag = gtid >> 6;      // frag = ks*4 + ot
        const int ks = frag >> 2, ot = frag & 3;
        const float* src = &W2[(ot * 32 + (lane & 31)) * 256 + ks * 16 + (lane >> 5) * 8];
        uint4 o;
        o.x = pk2h(src[0], src[1]);
        o.y = pk2h(src[2], src[3]);
        o.z = pk2h(src[4], src[5]);
        o.w = pk2h(src[6], src[7]);
        ((uint4*)w2f)[gtid] = o;
    } else {
        if (threadIdx.x < 128) gs[threadIdx.x] = 0.f;
    }
}

// ---------------------------------------------------------------------------
// Launch 2: attn_one — entire attention for 16 q-rows per block, all 4 heads.
// (unchanged from R15/R16/R17 — verified passing)
// ---------------------------------------------------------------------------
__launch_bounds__(512)
__global__ void attn_one(const unsigned short* __restrict__ q16,
                         const unsigned short* __restrict__ k16,
                         const unsigned short* __restrict__ v16t,
                         const float* __restrict__ outw, const float* __restrict__ outb,
                         const float* __restrict__ W1,
                         unsigned short* __restrict__ n1f, float* __restrict__ gs,
                         float* __restrict__ attn_out)
{
    extern __shared__ char smem[];
    float* ctx2 = (float*)(smem + 131072);
    float* il   = (float*)(smem + 147456);
    float* attr = (float*)smem;     // alias of P region (used after P is dead)

    const int tid = threadIdx.x;
    const int q0 = blockIdx.x * 16;
    const int lane = tid & 63, wv = tid >> 6;
    const int col = lane & 15, quad = lane >> 4;
    const int h = wv & 3, khalf = wv >> 2;
    const int prow = h * 16 + col;

    // ---- phase 1: scores -> P (f16, swizzled) ----
    {
        union { uint4 u; half8 h8; } bq;
        bq.u = *(const uint4*)&q16[(size_t)(q0 + col) * 128 + h * 32 + quad * 8];
        for (int kt = khalf * 32; kt < khalf * 32 + 32; kt++) {
            union { uint4 u; half8 h8; } ak;
            ak.u = *(const uint4*)&k16[(size_t)(kt * 16 + col) * 128 + h * 32 + quad * 8];
            floatx4 c = {0.f, 0.f, 0.f, 0.f};
            c = __builtin_amdgcn_mfma_f32_16x16x32_f16(ak.h8, bq.h8, c, 0, 0, 0);
            ushort4 o;
            o.x = f2h(c[0] * 0.17677669529663687f);
            o.y = f2h(c[1] * 0.17677669529663687f);
            o.z = f2h(c[2] * 0.17677669529663687f);
            o.w = f2h(c[3] * 0.17677669529663687f);
            *(ushort4*)(smem + plds(prow, kt * 32 + quad * 8)) = o;
        }
    }
    __syncthreads();

    // ---- phase 2: softmax stats; P := exp(s-m); il = 1/sum ----
    {
        const int row = tid >> 3, oct = tid & 7;
        char* rb = smem + row * 2048;
        const int swz = (row & 7) << 4;
        float mx = -1e30f;
#pragma unroll
        for (int i = 0; i < 16; i++) {
            uint4 v = *(uint4*)(rb + ((oct * 256 + i * 16) ^ swz));
            const unsigned short* pv = (const unsigned short*)&v;
#pragma unroll
            for (int j = 0; j < 8; j++) mx = fmaxf(mx, h2f(pv[j]));
        }
        mx = fmaxf(mx, __shfl_xor(mx, 1));
        mx = fmaxf(mx, __shfl_xor(mx, 2));
        mx = fmaxf(mx, __shfl_xor(mx, 4));
        float s = 0.f;
#pragma unroll
        for (int i = 0; i < 16; i++) {
            char* ap = rb + ((oct * 256 + i * 16) ^ swz);
            uint4 v = *(uint4*)ap;
            const unsigned short* pv = (const unsigned short*)&v;
            ushort4 w0, w1;
            float p0 = __expf(h2f(pv[0]) - mx), p1 = __expf(h2f(pv[1]) - mx);
            float p2 = __expf(h2f(pv[2]) - mx), p3 = __expf(h2f(pv[3]) - mx);
            float p4 = __expf(h2f(pv[4]) - mx), p5 = __expf(h2f(pv[5]) - mx);
            float p6 = __expf(h2f(pv[6]) - mx), p7 = __expf(h2f(pv[7]) - mx);
            s += p0 + p1 + p2 + p3 + p4 + p5 + p6 + p7;
            w0.x = f2h(p0); w0.y = f2h(p1); w0.z = f2h(p2); w0.w = f2h(p3);
            w1.x = f2h(p4); w1.y = f2h(p5); w1.z = f2h(p6); w1.w = f2h(p7);
            *(ushort4*)ap = w0;
            *(ushort4*)(ap + 8) = w1;
        }
        s += __shfl_xor(s, 1);
        s += __shfl_xor(s, 2);
        s += __shfl_xor(s, 4);
        if ((tid & 7) == 0) il[row] = 1.0f / s;
    }
    __syncthreads();

    // ---- phase 3a: PV via MFMA, scale by il, -> ctx2 ----
    {
        floatx4 acc[2] = {};
        for (int ks = khalf * 16; ks < khalf * 16 + 16; ks++) {
            union { uint4 u; half8 h8; } pf;
            pf.u = *(uint4*)(smem + plds(prow, ks * 64 + quad * 16));
#pragma unroll
            for (int dt = 0; dt < 2; dt++) {
                union { uint4 u; half8 h8; } vf;
                vf.u = *(const uint4*)&v16t[(size_t)(h * 32 + dt * 16 + col) * 1024 + ks * 32 + quad * 8];
                acc[dt] = __builtin_amdgcn_mfma_f32_16x16x32_f16(vf.h8, pf.h8, acc[dt], 0, 0, 0);
            }
        }
        const float sil = il[prow];
#pragma unroll
        for (int dt = 0; dt < 2; dt++) {
            *(float4*)&ctx2[(khalf * 16 + col) * 128 + h * 32 + dt * 16 + quad * 4] =
                make_float4(acc[dt][0] * sil, acc[dt][1] * sil, acc[dt][2] * sil, acc[dt][3] * sil);
        }
    }
    // ---- phase 3b: attn_w = 0.25 * sum_h P*il ----
    {
        const int q = tid >> 5, kc = tid & 31;
        const float s0 = il[q] * 0.25f, s1 = il[16 + q] * 0.25f;
        const float s2 = il[32 + q] * 0.25f, s3 = il[48 + q] * 0.25f;
#pragma unroll
        for (int b = 0; b < 4; b++) {
            const int kb = kc * 64 + b * 16;
            uint4 v0 = *(uint4*)(smem + plds(q, kb));
            uint4 v1 = *(uint4*)(smem + plds(16 + q, kb));
            uint4 v2 = *(uint4*)(smem + plds(32 + q, kb));
            uint4 v3 = *(uint4*)(smem + plds(48 + q, kb));
            const unsigned short* p0 = (const unsigned short*)&v0;
            const unsigned short* p1 = (const unsigned short*)&v1;
            const unsigned short* p2 = (const unsigned short*)&v2;
            const unsigned short* p3 = (const unsigned short*)&v3;
            float o[8];
#pragma unroll
            for (int j = 0; j < 8; j++)
                o[j] = h2f(p0[j]) * s0 + h2f(p1[j]) * s1 + h2f(p2[j]) * s2 + h2f(p3[j]) * s3;
            float* dst = &attn_out[(size_t)(q0 + q) * 1024 + kc * 32 + b * 8];
            *(float4*)dst = make_float4(o[0], o[1], o[2], o[3]);
            *(float4*)(dst + 4) = make_float4(o[4], o[5], o[6], o[7]);
        }
    }
    __syncthreads();

    // ---- phase 4: attended = ctx @ outw^T + outb -> attr ----
    {
        const int j = tid & 127, qh = tid >> 7;
        float a0 = outb[j], a1 = a0, a2 = a0, a3 = a0;
        const float* wr = &outw[j * 128];
        for (int d = 0; d < 128; d += 4) {
            float4 w = *(const float4*)&wr[d];
#pragma unroll
            for (int qq = 0; qq < 4; qq++) {
                const int q = qh * 4 + qq;
                float4 c0 = *(const float4*)&ctx2[q * 128 + d];
                float4 c1 = *(const float4*)&ctx2[(16 + q) * 128 + d];
                float dot = w.x * (c0.x + c1.x) + w.y * (c0.y + c1.y)
                          + w.z * (c0.z + c1.z) + w.w * (c0.w + c1.w);
                if (qq == 0) a0 += dot; else if (qq == 1) a1 += dot;
                else if (qq == 2) a2 += dot; else a3 += dot;
            }
        }
        attr[(qh * 4 + 0) * 128 + j] = a0;
        attr[(qh * 4 + 1) * 128 + j] = a1;
        attr[(qh * 4 + 2) * 128 + j] = a2;
        attr[(qh * 4 + 3) * 128 + j] = a3;
    }
    __syncthreads();

    // ---- phase 5: gs + n1 in MFMA B-fragment layout (n1f) ----
    if (tid < 128) {
        float s = 0.f;
#pragma unroll
        for (int q = 0; q < 16; q++) s += attr[q * 128 + tid];
        atomicAdd(&gs[tid], s);
    }
    {
        const int c = tid & 255, qh = tid >> 8;
        const float* wr = &W1[c * 256 + 128];
        float n[8] = {};
        for (int d = 0; d < 128; d += 4) {
            float4 w = *(const float4*)&wr[d];
#pragma unroll
            for (int qq = 0; qq < 8; qq++) {
                float4 a = *(const float4*)&attr[(qh * 8 + qq) * 128 + d];
                n[qq] += w.x * a.x + w.y * a.y + w.z * a.z + w.w * a.w;
            }
        }
        // fragment store: c = ks*16 + ko*8 + j ; lane = ko*32 + (n&31)
        const int j = c & 7, ko = (c >> 3) & 1, ks = c >> 4;
#pragma unroll
        for (int qq = 0; qq < 8; qq++) {
            const int nn = q0 + qh * 8 + qq;
            n1f[(size_t)((((nn >> 5) * 16 + ks) * 64 + ko * 32 + (nn & 31)) * 8 + j)] = f2h(n[qq]);
        }
    }
}

// ---------------------------------------------------------------------------
// Launch 3: matching scores, 32x32x16 MFMA, 4 waves/SIMD, KS-STAGGERED.
// grid (8, 65). 512 thr = 8 waves; wave = 32n x 1t (ns=wv&3, th=wv>>2);
// 8 phases x 2t. acc[4] = 64 AGPR. R18: wave wv sweeps ks=(kk+2*wv)&15 so
// concurrent waves hit different W2 ks-slices -> LDS arrivals de-bursted
// (convoy queueing was the last open theory for the ~2x idle around MFMA).
// ---------------------------------------------------------------------------
__launch_bounds__(512, 4)
__global__ void score_kernel(const unsigned short* __restrict__ t1h,
                             const unsigned short* __restrict__ n1f,
                             const unsigned short* __restrict__ w2f,
                             const float* __restrict__ b2, const float* __restrict__ W3,
                             const float* __restrict__ b3, float* __restrict__ out,
                             const float* __restrict__ gs,
                             const float* __restrict__ Wc1, const float* __restrict__ bc1,
                             const float* __restrict__ Wc2, const float* __restrict__ bc2,
                             float* __restrict__ outc)
{
    __shared__ unsigned short w2s[32768];   // 64 KB
    __shared__ float b2s[128], w3s[128];
    const int tid = threadIdx.x;

    if (blockIdx.y == 64) {
        if (blockIdx.x != 0) return;
        float* g  = (float*)w2s;
        float* hh = g + 128;
        if (tid < 128) g[tid] = gs[tid] * (1.0f / 1024.0f);
        __syncthreads();
        if (tid < 256) {
            float a = bc1[tid];
            const float* wr = &Wc1[tid * 128];
            for (int d = 0; d < 128; d += 4) {
                float4 w = *(const float4*)&wr[d];
                a += w.x * g[d] + w.y * g[d + 1] + w.z * g[d + 2] + w.w * g[d + 3];
            }
            hh[tid] = fmaxf(a, 0.f);
        }
        __syncthreads();
        if (tid < 32) {
            float a = bc2[tid];
            const float* wr = &Wc2[tid * 256];
            for (int c = 0; c < 256; c += 4) {
                float4 w = *(const float4*)&wr[c];
                a += w.x * hh[c] + w.y * hh[c + 1] + w.z * hh[c + 2] + w.w * hh[c + 3];
            }
            outc[tid] = a;
        }
        return;
    }

    const int lane = tid & 63;
    const int wv = tid >> 6;           // 0..7
    const int nc = lane & 31;          // n within wave
    const int ko = lane >> 5;          // k-octet selector
    const int ns = wv & 3;             // n-slice within block
    const int th = wv >> 2;            // t parity within phase
    const int nb = blockIdx.x * 128 + ns * 32;
    const int tb = blockIdx.y * 16;

    // stage W2 fragments + tables -> LDS (4096 uint4 over 512 threads)
    {
        const uint4* src = (const uint4*)w2f;
        uint4* dst = (uint4*)w2s;
#pragma unroll
        for (int i = 0; i < 8; i++) dst[tid + i * 512] = src[tid + i * 512];
        if (tid < 128) { b2s[tid] = b2[tid]; w3s[tid] = W3[tid]; }
    }

    // n1f base: nblk = bx*4 + ns; lane-contiguous 16B, ks-stride 1024B.
    const unsigned short* nfbase =
        n1f + ((size_t)(blockIdx.x * 4 + ns) * 16) * 512 + (size_t)lane * 8;
    const float b3s = b3[0];
    const int ksoff = wv * 2;          // per-wave ks stagger (de-convoy)
    __syncthreads();

    for (int ph = 0; ph < 8; ph++) {
        const int t = tb + ph * 2 + th;
        const unsigned short* tp_b = t1h + (size_t)t * 256 + ko * 8;
        floatx16 acc[4] = {};   // zero-init; b2 folded in epilogue

#pragma unroll
        for (int kk = 0; kk < 16; kk++) {
            const int ks = (kk + ksoff) & 15;   // staggered sweep, sum commutes
            uint4 np = *(const uint4*)(nfbase + (size_t)ks * 512);
            uint4 tp = *(const uint4*)(tp_b + ks * 16);
            const unsigned* npu = (const unsigned*)&np;
            const unsigned* tpu = (const unsigned*)&tp;
            union { unsigned u[4]; half8 h; } af;
#pragma unroll
            for (int p = 0; p < 4; p++)
                af.u[p] = pkmax(pkadd(tpu[p], npu[p]), 0u);
#pragma unroll
            for (int ot = 0; ot < 4; ot++) {
                union { uint4 u; half8 h; } bf;
                bf.u = *(const uint4*)&w2s[((ks * 4 + ot) * 64 + lane) * 8];
                acc[ot] = __builtin_amdgcn_mfma_f32_32x32x16_f16(bf.h, af.h, acc[ot], 0, 0, 0);
            }
        }

        // epilogue: +b2, relu, *W3, in-lane reduce over 64 dims, then one
        // shfl_xor(32) combines the two ko-halves.
        float part = 0.f;
#pragma unroll
        for (int ot = 0; ot < 4; ot++) {
            floatx16 a0 = acc[ot];
#pragma unroll
            for (int g = 0; g < 4; g++) {
                float4 bq = *(const float4*)&b2s[ot * 32 + g * 8 + ko * 4];
                float4 wq = *(const float4*)&w3s[ot * 32 + g * 8 + ko * 4];
                part += fmaxf(a0[g * 4 + 0] + bq.x, 0.f) * wq.x
                      + fmaxf(a0[g * 4 + 1] + bq.y, 0.f) * wq.y
                      + fmaxf(a0[g * 4 + 2] + bq.z, 0.f) * wq.z
                      + fmaxf(a0[g * 4 + 3] + bq.w, 0.f) * wq.w;
            }
        }
        part += __shfl_xor(part, 32);
        if (lane < 32) {
            out[(size_t)t * 1024 + nb + nc] =
                1.0f / (1.0f + __expf(-(part + b3s)));
        }
    }
}

// ---------------------------------------------------------------------------
extern "C" void kernel_launch(void* const* d_in, const int* in_sizes, int n_in,
                              void* d_out, int out_size, void* d_ws, size_t ws_size,
                              hipStream_t stream)
{
    const float* node = (const float*)d_in[0];
    const float* task = (const float*)d_in[1];
    const float* ipw  = (const float*)d_in[2];
    const float* ipb  = (const float*)d_in[3];
    const float* outw = (const float*)d_in[4];
    const float* outb = (const float*)d_in[5];
    const float* W1   = (const float*)d_in[6];
    const float* b1   = (const float*)d_in[7];
    const float* W2   = (const float*)d_in[8];
    const float* b2   = (const float*)d_in[9];
    const float* W3   = (const float*)d_in[10];
    const float* b3   = (const float*)d_in[11];
    const float* Wc1  = (const float*)d_in[12];
    const float* bc1  = (const float*)d_in[13];
    const float* Wc2  = (const float*)d_in[14];
    const float* bc2  = (const float*)d_in[15];

    char* ws = (char*)d_ws;
    float* qkv = (float*)(ws + OFF_QKV);
    unsigned short* q16 = (unsigned short*)(ws + OFF_Q16);
    unsigned short* k16 = (unsigned short*)(ws + OFF_K16);
    unsigned short* v16t = (unsigned short*)(ws + OFF_V16);
    unsigned short* t1h = (unsigned short*)(ws + OFF_T1H);
    unsigned short* n1f = (unsigned short*)(ws + OFF_N1F);
    unsigned short* w2f = (unsigned short*)(ws + OFF_W2F);
    float* gs = (float*)(ws + OFF_GS);

    float* out_match = (float*)d_out;
    float* out_coord = out_match + 1048576;
    float* out_attn  = out_coord + 32;

    // allow 144KB dynamic LDS for attn_one (idempotent; not a stream op)
    static bool attr_set = false;
    if (!attr_set) {
        hipFuncSetAttribute((const void*)attn_one,
                            hipFuncAttributeMaxDynamicSharedMemorySize, 147712);
        attr_set = true;
    }

    // 1. qkv (+f16 q/k/vT) + t1h + w2prep(32x32 layout) + gs zero
    proj_fused<<<dim3(177, 1, 1), 256, 0, stream>>>(
        node, ipw, ipb, task, W1, b1, W2, qkv, t1h, w2f, gs, q16, k16, v16t);
    // 2. full attention: scores+softmax+attn_w+PV+outproj+gs+n1f
    attn_one<<<dim3(64, 1, 1), 512, 147712, stream>>>(
        q16, k16, v16t, outw, outb, W1, n1f, gs, out_attn);
    // 3. matching scores (32x32x16, 4 waves/SIMD, ks-staggered) + coord head
    score_kernel<<<dim3(8, 65, 1), 512, 0, stream>>>(
        t1h, n1f, w2f, b2, W3, b3, out_match,
        gs, Wc1, bc1, Wc2, bc2, out_coord);
}

// Round 13
// 200.993 us; speedup vs baseline: 1.2668x; 1.2668x over previous
//
#include <hip/hip_runtime.h>
#include <hip/hip_fp16.h>
#include <stdint.h>

// ---------------------------------------------------------------------------
// ClusterPolicyNetwork. FINAL (R19 = R16 revert): R18's ks-stagger made LDS/
// global addressing runtime-dependent -> register demand > 128 cap -> scratch
// spill (FETCH 187MB). Reverted to R16, the best verified configuration.
//
// Session ledger for score_kernel (the dominant kernel, 78us = ~880 TF eff):
//   falsified: reg slack (R16), prefetch (R10), MFMA shape 16x16->32x32
//   (R14), LDS traffic halving (R11), operand location L2/L1/reg (R15/R16),
//   occupancy 2->4 waves/SIMD (R17), ks-stagger (R18, invalid: spill).
//   ~880 TF == the documented plain-HIP simple-structure ceiling (m97 class,
//   m99-m141); past it needs the 8-phase+counted-vmcnt combo whose
//   prerequisites (global-staged deep K pipeline) don't exist at K=256 with
//   LDS-resident weights.
// Launches: proj_fused -> attn_one -> score_kernel (3).
// d_out: matching[1M]|coord[32]|attn_w[1M]
// ---------------------------------------------------------------------------

typedef __attribute__((ext_vector_type(4))) float floatx4;
typedef __attribute__((ext_vector_type(16))) float floatx16;
typedef __attribute__((ext_vector_type(8))) _Float16 half8;

// workspace offsets (bytes)
#define OFF_QKV  0x000000u    // 1024*384*4
#define OFF_Q16  0x180000u    // 1024*128*2
#define OFF_K16  0x1C0000u    // 1024*128*2
#define OFF_V16  0x200000u    // 128*1024*2 (V^T, d-major)
#define OFF_T1H  0x280000u    // 1024*256*2 (f16, includes +b1)
#define OFF_N1F  0x300000u    // 1024*256*2 (f16, MFMA B-fragment layout)
#define OFF_W2F  0x380000u    // 65536 (f16 MFMA frags, 32x32 layout)
#define OFF_GS   0x398000u    // 128*4

__device__ __forceinline__ unsigned pkadd(unsigned a, unsigned b) {
    unsigned r; asm("v_pk_add_f16 %0, %1, %2" : "=v"(r) : "v"(a), "v"(b)); return r;
}
__device__ __forceinline__ unsigned pkmax(unsigned a, unsigned b) {
    unsigned r; asm("v_pk_max_f16 %0, %1, %2" : "=v"(r) : "v"(a), "v"(b)); return r;
}
__device__ __forceinline__ unsigned pk2h(float a, float b) {
    return (unsigned)__half_as_ushort(__float2half(a)) |
           ((unsigned)__half_as_ushort(__float2half(b)) << 16);
}
__device__ __forceinline__ float h2f(unsigned short u) {
    return __half2float(__ushort_as_half(u));
}
__device__ __forceinline__ unsigned short f2h(float v) {
    return __half_as_ushort(__float2half(v));
}
// P-LDS swizzled byte offset: row-major [64 rows][2048 B], XOR bank swizzle
__device__ __forceinline__ int plds(int row, int kb) {
    return row * 2048 + (((kb & ~15) ^ ((row & 7) << 4))) + (kb & 15);
}

// ---------------------------------------------------------------------------
// fp32 GEMM tile body: C = scale*(A @ B^T) [+ bias], 64x64 tile, 256 thr.
// SIDE: also emit f16 side-copies (q16/k16 row-major, v16t d-major).
// ---------------------------------------------------------------------------
template<bool BIAS, bool F16OUT, bool SIDE>
__device__ __forceinline__ void gemm_dev(
    const float* __restrict__ A, int lda,
    const float* __restrict__ B, int ldb,
    const float* __restrict__ bias,
    void* __restrict__ Cv, int ldc, int K, float scale,
    int m0, int n0, float (*As)[64], float (*Bs)[64],
    unsigned short* __restrict__ q16o,
    unsigned short* __restrict__ k16o,
    unsigned short* __restrict__ v16o)
{
    const int tid = threadIdx.x;
    const int tx = tid & 15, ty = tid >> 4;
    const int lr = tid >> 2;
    const int lk = (tid & 3) * 4;
    float c[4][4] = {};

    for (int k0 = 0; k0 < K; k0 += 16) {
        float4 a  = *(const float4*)&A[(long)(m0 + lr) * lda + k0 + lk];
        float4 bb = *(const float4*)&B[(long)(n0 + lr) * ldb + k0 + lk];
        __syncthreads();
        As[lk + 0][lr] = a.x;  As[lk + 1][lr] = a.y;  As[lk + 2][lr] = a.z;  As[lk + 3][lr] = a.w;
        Bs[lk + 0][lr] = bb.x; Bs[lk + 1][lr] = bb.y; Bs[lk + 2][lr] = bb.z; Bs[lk + 3][lr] = bb.w;
        __syncthreads();
#pragma unroll
        for (int k = 0; k < 16; k++) {
            float4 av = *(const float4*)&As[k][ty * 4];
            float4 bv = *(const float4*)&Bs[k][tx * 4];
            c[0][0] += av.x * bv.x; c[0][1] += av.x * bv.y; c[0][2] += av.x * bv.z; c[0][3] += av.x * bv.w;
            c[1][0] += av.y * bv.x; c[1][1] += av.y * bv.y; c[1][2] += av.y * bv.z; c[1][3] += av.y * bv.w;
            c[2][0] += av.z * bv.x; c[2][1] += av.z * bv.y; c[2][2] += av.z * bv.z; c[2][3] += av.z * bv.w;
            c[3][0] += av.w * bv.x; c[3][1] += av.w * bv.y; c[3][2] += av.w * bv.z; c[3][3] += av.w * bv.w;
        }
    }

    float bsv[4] = {0.f, 0.f, 0.f, 0.f};
    if (BIAS) {
        float4 t = *(const float4*)&bias[n0 + tx * 4];
        bsv[0] = t.x; bsv[1] = t.y; bsv[2] = t.z; bsv[3] = t.w;
    }
    const int gcol = n0 + tx * 4;
#pragma unroll
    for (int i = 0; i < 4; i++) {
        float v0 = c[i][0] * scale + bsv[0];
        float v1 = c[i][1] * scale + bsv[1];
        float v2 = c[i][2] * scale + bsv[2];
        float v3 = c[i][3] * scale + bsv[3];
        long m = m0 + ty * 4 + i;
        if (F16OUT) {
            unsigned short* Cp = (unsigned short*)Cv;
            ushort4 o;
            o.x = f2h(v0); o.y = f2h(v1); o.z = f2h(v2); o.w = f2h(v3);
            *(ushort4*)&Cp[m * ldc + n0 + tx * 4] = o;
        } else {
            float* Cp = (float*)Cv;
            *(float4*)&Cp[m * ldc + n0 + tx * 4] = make_float4(v0, v1, v2, v3);
        }
        if (SIDE) {
            ushort4 o;
            o.x = f2h(v0); o.y = f2h(v1); o.z = f2h(v2); o.w = f2h(v3);
            if (gcol < 128) {
                *(ushort4*)&q16o[m * 128 + gcol] = o;
            } else if (gcol < 256) {
                *(ushort4*)&k16o[m * 128 + (gcol - 128)] = o;
            } else {
                v16o[(size_t)(gcol - 256 + 0) * 1024 + m] = o.x;
                v16o[(size_t)(gcol - 256 + 1) * 1024 + m] = o.y;
                v16o[(size_t)(gcol - 256 + 2) * 1024 + m] = o.z;
                v16o[(size_t)(gcol - 256 + 3) * 1024 + m] = o.w;
            }
        }
    }
}

// ---------------------------------------------------------------------------
// Launch 1: qkv gemm (96, +f16 sides) + t1h gemm (64) + w2prep (16) + gs zero
// w2prep emits the 32x32x16 A-fragment layout (R14-verified):
//   frag id f = ks*4 + ot;  w2f[(f*64+lane)*8+j] =
//   f16(W2[ot*32 + (lane&31)][ks*16 + (lane>>5)*8 + j])
// ---------------------------------------------------------------------------
__launch_bounds__(256)
__global__ void proj_fused(const float* __restrict__ node, const float* __restrict__ ipw,
                           const float* __restrict__ ipb,
                           const float* __restrict__ task, const float* __restrict__ W1,
                           const float* __restrict__ b1, const float* __restrict__ W2,
                           float* __restrict__ qkv, unsigned short* __restrict__ t1h,
                           unsigned short* __restrict__ w2f, float* __restrict__ gs,
                           unsigned short* __restrict__ q16,
                           unsigned short* __restrict__ k16,
                           unsigned short* __restrict__ v16t)
{
    __shared__ float As[16][64], Bs[16][64];
    const int bid = blockIdx.x;
    if (bid < 96) {
        gemm_dev<true, false, true>(node, 128, ipw, 128, ipb, qkv, 384, 128, 1.0f,
                                    (bid & 15) * 64, (bid >> 4) * 64, As, Bs,
                                    q16, k16, v16t);
    } else if (bid < 160) {
        const int b = bid - 96;
        gemm_dev<true, true, false>(task, 128, W1, 256, b1, t1h, 256, 128, 1.0f,
                                    (b & 15) * 64, (b >> 4) * 64, As, Bs,
                                    nullptr, nullptr, nullptr);
    } else if (bid < 176) {
        const int gtid = (bid - 160) * 256 + threadIdx.x;  // 0..4095
        const int lane = gtid & 63, frag = gtid >> 6;      // frag = ks*4 + ot
        const int ks = frag >> 2, ot = frag & 3;
        const float* src = &W2[(ot * 32 + (lane & 31)) * 256 + ks * 16 + (lane >> 5) * 8];
        uint4 o;
        o.x = pk2h(src[0], src[1]);
        o.y = pk2h(src[2], src[3]);
        o.z = pk2h(src[4], src[5]);
        o.w = pk2h(src[6], src[7]);
        ((uint4*)w2f)[gtid] = o;
    } else {
        if (threadIdx.x < 128) gs[threadIdx.x] = 0.f;
    }
}

// ---------------------------------------------------------------------------
// Launch 2: attn_one — entire attention for 16 q-rows per block, all 4 heads.
// (verified passing since R13)
// ---------------------------------------------------------------------------
__launch_bounds__(512)
__global__ void attn_one(const unsigned short* __restrict__ q16,
                         const unsigned short* __restrict__ k16,
                         const unsigned short* __restrict__ v16t,
                         const float* __restrict__ outw, const float* __restrict__ outb,
                         const float* __restrict__ W1,
                         unsigned short* __restrict__ n1f, float* __restrict__ gs,
                         float* __restrict__ attn_out)
{
    extern __shared__ char smem[];
    float* ctx2 = (float*)(smem + 131072);
    float* il   = (float*)(smem + 147456);
    float* attr = (float*)smem;     // alias of P region (used after P is dead)

    const int tid = threadIdx.x;
    const int q0 = blockIdx.x * 16;
    const int lane = tid & 63, wv = tid >> 6;
    const int col = lane & 15, quad = lane >> 4;
    const int h = wv & 3, khalf = wv >> 2;
    const int prow = h * 16 + col;

    // ---- phase 1: scores -> P (f16, swizzled) ----
    {
        union { uint4 u; half8 h8; } bq;
        bq.u = *(const uint4*)&q16[(size_t)(q0 + col) * 128 + h * 32 + quad * 8];
        for (int kt = khalf * 32; kt < khalf * 32 + 32; kt++) {
            union { uint4 u; half8 h8; } ak;
            ak.u = *(const uint4*)&k16[(size_t)(kt * 16 + col) * 128 + h * 32 + quad * 8];
            floatx4 c = {0.f, 0.f, 0.f, 0.f};
            c = __builtin_amdgcn_mfma_f32_16x16x32_f16(ak.h8, bq.h8, c, 0, 0, 0);
            ushort4 o;
            o.x = f2h(c[0] * 0.17677669529663687f);
            o.y = f2h(c[1] * 0.17677669529663687f);
            o.z = f2h(c[2] * 0.17677669529663687f);
            o.w = f2h(c[3] * 0.17677669529663687f);
            *(ushort4*)(smem + plds(prow, kt * 32 + quad * 8)) = o;
        }
    }
    __syncthreads();

    // ---- phase 2: softmax stats; P := exp(s-m); il = 1/sum ----
    {
        const int row = tid >> 3, oct = tid & 7;
        char* rb = smem + row * 2048;
        const int swz = (row & 7) << 4;
        float mx = -1e30f;
#pragma unroll
        for (int i = 0; i < 16; i++) {
            uint4 v = *(uint4*)(rb + ((oct * 256 + i * 16) ^ swz));
            const unsigned short* pv = (const unsigned short*)&v;
#pragma unroll
            for (int j = 0; j < 8; j++) mx = fmaxf(mx, h2f(pv[j]));
        }
        mx = fmaxf(mx, __shfl_xor(mx, 1));
        mx = fmaxf(mx, __shfl_xor(mx, 2));
        mx = fmaxf(mx, __shfl_xor(mx, 4));
        float s = 0.f;
#pragma unroll
        for (int i = 0; i < 16; i++) {
            char* ap = rb + ((oct * 256 + i * 16) ^ swz);
            uint4 v = *(uint4*)ap;
            const unsigned short* pv = (const unsigned short*)&v;
            ushort4 w0, w1;
            float p0 = __expf(h2f(pv[0]) - mx), p1 = __expf(h2f(pv[1]) - mx);
            float p2 = __expf(h2f(pv[2]) - mx), p3 = __expf(h2f(pv[3]) - mx);
            float p4 = __expf(h2f(pv[4]) - mx), p5 = __expf(h2f(pv[5]) - mx);
            float p6 = __expf(h2f(pv[6]) - mx), p7 = __expf(h2f(pv[7]) - mx);
            s += p0 + p1 + p2 + p3 + p4 + p5 + p6 + p7;
            w0.x = f2h(p0); w0.y = f2h(p1); w0.z = f2h(p2); w0.w = f2h(p3);
            w1.x = f2h(p4); w1.y = f2h(p5); w1.z = f2h(p6); w1.w = f2h(p7);
            *(ushort4*)ap = w0;
            *(ushort4*)(ap + 8) = w1;
        }
        s += __shfl_xor(s, 1);
        s += __shfl_xor(s, 2);
        s += __shfl_xor(s, 4);
        if ((tid & 7) == 0) il[row] = 1.0f / s;
    }
    __syncthreads();

    // ---- phase 3a: PV via MFMA, scale by il, -> ctx2 ----
    {
        floatx4 acc[2] = {};
        for (int ks = khalf * 16; ks < khalf * 16 + 16; ks++) {
            union { uint4 u; half8 h8; } pf;
            pf.u = *(uint4*)(smem + plds(prow, ks * 64 + quad * 16));
#pragma unroll
            for (int dt = 0; dt < 2; dt++) {
                union { uint4 u; half8 h8; } vf;
                vf.u = *(const uint4*)&v16t[(size_t)(h * 32 + dt * 16 + col) * 1024 + ks * 32 + quad * 8];
                acc[dt] = __builtin_amdgcn_mfma_f32_16x16x32_f16(vf.h8, pf.h8, acc[dt], 0, 0, 0);
            }
        }
        const float sil = il[prow];
#pragma unroll
        for (int dt = 0; dt < 2; dt++) {
            *(float4*)&ctx2[(khalf * 16 + col) * 128 + h * 32 + dt * 16 + quad * 4] =
                make_float4(acc[dt][0] * sil, acc[dt][1] * sil, acc[dt][2] * sil, acc[dt][3] * sil);
        }
    }
    // ---- phase 3b: attn_w = 0.25 * sum_h P*il ----
    {
        const int q = tid >> 5, kc = tid & 31;
        const float s0 = il[q] * 0.25f, s1 = il[16 + q] * 0.25f;
        const float s2 = il[32 + q] * 0.25f, s3 = il[48 + q] * 0.25f;
#pragma unroll
        for (int b = 0; b < 4; b++) {
            const int kb = kc * 64 + b * 16;
            uint4 v0 = *(uint4*)(smem + plds(q, kb));
            uint4 v1 = *(uint4*)(smem + plds(16 + q, kb));
            uint4 v2 = *(uint4*)(smem + plds(32 + q, kb));
            uint4 v3 = *(uint4*)(smem + plds(48 + q, kb));
            const unsigned short* p0 = (const unsigned short*)&v0;
            const unsigned short* p1 = (const unsigned short*)&v1;
            const unsigned short* p2 = (const unsigned short*)&v2;
            const unsigned short* p3 = (const unsigned short*)&v3;
            float o[8];
#pragma unroll
            for (int j = 0; j < 8; j++)
                o[j] = h2f(p0[j]) * s0 + h2f(p1[j]) * s1 + h2f(p2[j]) * s2 + h2f(p3[j]) * s3;
            float* dst = &attn_out[(size_t)(q0 + q) * 1024 + kc * 32 + b * 8];
            *(float4*)dst = make_float4(o[0], o[1], o[2], o[3]);
            *(float4*)(dst + 4) = make_float4(o[4], o[5], o[6], o[7]);
        }
    }
    __syncthreads();

    // ---- phase 4: attended = ctx @ outw^T + outb -> attr ----
    {
        const int j = tid & 127, qh = tid >> 7;
        float a0 = outb[j], a1 = a0, a2 = a0, a3 = a0;
        const float* wr = &outw[j * 128];
        for (int d = 0; d < 128; d += 4) {
            float4 w = *(const float4*)&wr[d];
#pragma unroll
            for (int qq = 0; qq < 4; qq++) {
                const int q = qh * 4 + qq;
                float4 c0 = *(const float4*)&ctx2[q * 128 + d];
                float4 c1 = *(const float4*)&ctx2[(16 + q) * 128 + d];
                float dot = w.x * (c0.x + c1.x) + w.y * (c0.y + c1.y)
                          + w.z * (c0.z + c1.z) + w.w * (c0.w + c1.w);
                if (qq == 0) a0 += dot; else if (qq == 1) a1 += dot;
                else if (qq == 2) a2 += dot; else a3 += dot;
            }
        }
        attr[(qh * 4 + 0) * 128 + j] = a0;
        attr[(qh * 4 + 1) * 128 + j] = a1;
        attr[(qh * 4 + 2) * 128 + j] = a2;
        attr[(qh * 4 + 3) * 128 + j] = a3;
    }
    __syncthreads();

    // ---- phase 5: gs + n1 in MFMA B-fragment layout (n1f) ----
    if (tid < 128) {
        float s = 0.f;
#pragma unroll
        for (int q = 0; q < 16; q++) s += attr[q * 128 + tid];
        atomicAdd(&gs[tid], s);
    }
    {
        const int c = tid & 255, qh = tid >> 8;
        const float* wr = &W1[c * 256 + 128];
        float n[8] = {};
        for (int d = 0; d < 128; d += 4) {
            float4 w = *(const float4*)&wr[d];
#pragma unroll
            for (int qq = 0; qq < 8; qq++) {
                float4 a = *(const float4*)&attr[(qh * 8 + qq) * 128 + d];
                n[qq] += w.x * a.x + w.y * a.y + w.z * a.z + w.w * a.w;
            }
        }
        // fragment store: c = ks*16 + ko*8 + j ; lane = ko*32 + (n&31)
        const int j = c & 7, ko = (c >> 3) & 1, ks = c >> 4;
#pragma unroll
        for (int qq = 0; qq < 8; qq++) {
            const int nn = q0 + qh * 8 + qq;
            n1f[(size_t)((((nn >> 5) * 16 + ks) * 64 + ko * 32 + (nn & 31)) * 8 + j)] = f2h(n[qq]);
        }
    }
}

// ---------------------------------------------------------------------------
// Launch 3: matching scores, 32x32x16 MFMA (R16, best verified). grid (8,65).
// 256 thr = 4 waves; wave = 32n x 2t; acc[2][4] = 128 AGPR; np persistent in
// registers (np_r[16], no tg dependence); tp wave-uniform L1-hot; bf from
// LDS. 78us = ~880 TF effective = documented plain-HIP simple-loop ceiling.
// ---------------------------------------------------------------------------
__launch_bounds__(256, 2)
__global__ void score_kernel(const unsigned short* __restrict__ t1h,
                             const unsigned short* __restrict__ n1f,
                             const unsigned short* __restrict__ w2f,
                             const float* __restrict__ b2, const float* __restrict__ W3,
                             const float* __restrict__ b3, float* __restrict__ out,
                             const float* __restrict__ gs,
                             const float* __restrict__ Wc1, const float* __restrict__ bc1,
                             const float* __restrict__ Wc2, const float* __restrict__ bc2,
                             float* __restrict__ outc)
{
    __shared__ unsigned short w2s[32768];   // 64 KB
    __shared__ float b2s[128], w3s[128];
    const int tid = threadIdx.x;

    if (blockIdx.y == 64) {
        if (blockIdx.x != 0) return;
        float* g  = (float*)w2s;
        float* hh = g + 128;
        if (tid < 128) g[tid] = gs[tid] * (1.0f / 1024.0f);
        __syncthreads();
        {
            float a = bc1[tid];
            const float* wr = &Wc1[tid * 128];
            for (int d = 0; d < 128; d += 4) {
                float4 w = *(const float4*)&wr[d];
                a += w.x * g[d] + w.y * g[d + 1] + w.z * g[d + 2] + w.w * g[d + 3];
            }
            hh[tid] = fmaxf(a, 0.f);
        }
        __syncthreads();
        if (tid < 32) {
            float a = bc2[tid];
            const float* wr = &Wc2[tid * 256];
            for (int c = 0; c < 256; c += 4) {
                float4 w = *(const float4*)&wr[c];
                a += w.x * hh[c] + w.y * hh[c + 1] + w.z * hh[c + 2] + w.w * hh[c + 3];
            }
            outc[tid] = a;
        }
        return;
    }

    const int lane = tid & 63;
    const int wv = tid >> 6;
    const int nc = lane & 31;          // n within wave
    const int ko = lane >> 5;          // k-octet selector
    const int nb = blockIdx.x * 128 + wv * 32;
    const int tb = blockIdx.y * 16;

    // stage W2 fragments + tables -> LDS (4096 uint4 over 256 threads)
    {
        const uint4* src = (const uint4*)w2f;
        uint4* dst = (uint4*)w2s;
#pragma unroll
        for (int i = 0; i < 16; i++) dst[tid + i * 256] = src[tid + i * 256];
        if (tid < 128) { b2s[tid] = b2[tid]; w3s[tid] = W3[tid]; }
    }

    // n1f base for this wave's n-block: nblk = bx*4 + wv; lane-contiguous.
    const unsigned short* nfbase =
        n1f + ((size_t)(blockIdx.x * 4 + wv) * 16) * 512 + (size_t)lane * 8;
    const unsigned short* tbase = t1h + (size_t)tb * 256 + ko * 8;
    const float b3s = b3[0];

    // PERSISTENT np fragments: no tg dependence -> load once (64 VGPR).
    uint4 np_r[16];
#pragma unroll
    for (int ks = 0; ks < 16; ks++)
        np_r[ks] = *(const uint4*)(nfbase + (size_t)ks * 512);

    __syncthreads();

    for (int tg = 0; tg < 8; tg++) {
        floatx16 acc[2][4] = {};   // zero-init; b2 folded in epilogue

#pragma unroll
        for (int ks = 0; ks < 16; ks++) {
            // register-resident np; broadcast tp (1KB active, L1-hot)
            uint4 tp0 = *(const uint4*)(tbase + (size_t)(tg * 2 + 0) * 256 + ks * 16);
            uint4 tp1 = *(const uint4*)(tbase + (size_t)(tg * 2 + 1) * 256 + ks * 16);

            const unsigned* npu = (const unsigned*)&np_r[ks];
            const unsigned* t0u = (const unsigned*)&tp0;
            const unsigned* t1u = (const unsigned*)&tp1;
            union { unsigned u[4]; half8 h; } af0, af1;
#pragma unroll
            for (int p = 0; p < 4; p++) {
                af0.u[p] = pkmax(pkadd(t0u[p], npu[p]), 0u);
                af1.u[p] = pkmax(pkadd(t1u[p], npu[p]), 0u);
            }
#pragma unroll
            for (int ot = 0; ot < 4; ot++) {
                union { uint4 u; half8 h; } bf;
                bf.u = *(const uint4*)&w2s[((ks * 4 + ot) * 64 + lane) * 8];
                acc[0][ot] = __builtin_amdgcn_mfma_f32_32x32x16_f16(bf.h, af0.h, acc[0][ot], 0, 0, 0);
                acc[1][ot] = __builtin_amdgcn_mfma_f32_32x32x16_f16(bf.h, af1.h, acc[1][ot], 0, 0, 0);
            }
        }

        // epilogue: +b2, relu, *W3, in-lane reduce over 64 dims, then one
        // shfl_xor(32) combines the two ko-halves.
        float part0 = 0.f, part1 = 0.f;
#pragma unroll
        for (int ot = 0; ot < 4; ot++) {
            floatx16 a0 = acc[0][ot];
            floatx16 a1 = acc[1][ot];
#pragma unroll
            for (int g = 0; g < 4; g++) {
                float4 bq = *(const float4*)&b2s[ot * 32 + g * 8 + ko * 4];
                float4 wq = *(const float4*)&w3s[ot * 32 + g * 8 + ko * 4];
                part0 += fmaxf(a0[g * 4 + 0] + bq.x, 0.f) * wq.x
                       + fmaxf(a0[g * 4 + 1] + bq.y, 0.f) * wq.y
                       + fmaxf(a0[g * 4 + 2] + bq.z, 0.f) * wq.z
                       + fmaxf(a0[g * 4 + 3] + bq.w, 0.f) * wq.w;
                part1 += fmaxf(a1[g * 4 + 0] + bq.x, 0.f) * wq.x
                       + fmaxf(a1[g * 4 + 1] + bq.y, 0.f) * wq.y
                       + fmaxf(a1[g * 4 + 2] + bq.z, 0.f) * wq.z
                       + fmaxf(a1[g * 4 + 3] + bq.w, 0.f) * wq.w;
            }
        }
        part0 += __shfl_xor(part0, 32);
        part1 += __shfl_xor(part1, 32);
        if (lane < 32) {
            out[(size_t)(tb + tg * 2 + 0) * 1024 + nb + nc] =
                1.0f / (1.0f + __expf(-(part0 + b3s)));
            out[(size_t)(tb + tg * 2 + 1) * 1024 + nb + nc] =
                1.0f / (1.0f + __expf(-(part1 + b3s)));
        }
    }
}

// ---------------------------------------------------------------------------
extern "C" void kernel_launch(void* const* d_in, const int* in_sizes, int n_in,
                              void* d_out, int out_size, void* d_ws, size_t ws_size,
                              hipStream_t stream)
{
    const float* node = (const float*)d_in[0];
    const float* task = (const float*)d_in[1];
    const float* ipw  = (const float*)d_in[2];
    const float* ipb  = (const float*)d_in[3];
    const float* outw = (const float*)d_in[4];
    const float* outb = (const float*)d_in[5];
    const float* W1   = (const float*)d_in[6];
    const float* b1   = (const float*)d_in[7];
    const float* W2   = (const float*)d_in[8];
    const float* b2   = (const float*)d_in[9];
    const float* W3   = (const float*)d_in[10];
    const float* b3   = (const float*)d_in[11];
    const float* Wc1  = (const float*)d_in[12];
    const float* bc1  = (const float*)d_in[13];
    const float* Wc2  = (const float*)d_in[14];
    const float* bc2  = (const float*)d_in[15];

    char* ws = (char*)d_ws;
    float* qkv = (float*)(ws + OFF_QKV);
    unsigned short* q16 = (unsigned short*)(ws + OFF_Q16);
    unsigned short* k16 = (unsigned short*)(ws + OFF_K16);
    unsigned short* v16t = (unsigned short*)(ws + OFF_V16);
    unsigned short* t1h = (unsigned short*)(ws + OFF_T1H);
    unsigned short* n1f = (unsigned short*)(ws + OFF_N1F);
    unsigned short* w2f = (unsigned short*)(ws + OFF_W2F);
    float* gs = (float*)(ws + OFF_GS);

    float* out_match = (float*)d_out;
    float* out_coord = out_match + 1048576;
    float* out_attn  = out_coord + 32;

    // allow 144KB dynamic LDS for attn_one (idempotent; not a stream op)
    static bool attr_set = false;
    if (!attr_set) {
        hipFuncSetAttribute((const void*)attn_one,
                            hipFuncAttributeMaxDynamicSharedMemorySize, 147712);
        attr_set = true;
    }

    // 1. qkv (+f16 q/k/vT) + t1h + w2prep(32x32 layout) + gs zero
    proj_fused<<<dim3(177, 1, 1), 256, 0, stream>>>(
        node, ipw, ipb, task, W1, b1, W2, qkv, t1h, w2f, gs, q16, k16, v16t);
    // 2. full attention: scores+softmax+attn_w+PV+outproj+gs+n1f
    attn_one<<<dim3(64, 1, 1), 512, 147712, stream>>>(
        q16, k16, v16t, outw, outb, W1, n1f, gs, out_attn);
    // 3. matching scores (32x32x16, persistent-np — best verified) + coord
    score_kernel<<<dim3(8, 65, 1), 256, 0, stream>>>(
        t1h, n1f, w2f, b2, W3, b3, out_match,
        gs, Wc1, bc1, Wc2, bc2, out_coord);
}